// Round 7
// baseline (199.607 us; speedup 1.0000x reference)
//
#include <hip/hip_runtime.h>
#include <hip/hip_bf16.h>

#define K_CLS 20
#define HIN 480
#define WIN 640
#define NPIX (HIN * WIN)
#define C_ 512
#define H_ 30
#define W_ 40
#define HW_ (H_ * W_)
#define NB_ 5
#define CNT_THRESH 10000
// out layout (fp32): pool_x[2048], NB, N, x_cropped[6*4*512*30*40]
#define XCROP_ELEMS (6 * 4 * C_ * H_ * W_)
#define ELEMS_PER_SN (C_ * H_ * W_)            // 614400 = one (s,n) slice
#define OUT_TOTAL (2050 + XCROP_ELEMS)

#define NBLK_STATS 300                 // NPIX/4/256 exactly
#define NODE_OFF (NBLK_STATS * 100)    // ws int offset of the 5 node boxes

// native clang vector types: __builtin_nontemporal_store rejects
// HIP_vector_type (R5 compile fail) but accepts ext_vector_type.
typedef float f32x2 __attribute__((ext_vector_type(2)));
typedef float f32x4 __attribute__((ext_vector_type(4)));

// fuse_k geometry (R7): block = one (n, 4-channel group); 512 blocks x 512.
// R6 null (occupancy 2x + NT stores: -0.3us) killed the latency theory.
// Remaining structural overhead: each of 2560 blocks re-staged the same
// (n,cgroup) slice (5x redundant) and paid its own stage->barrier stall
// before only 1200 positions of work. Now: stage ONCE, fuse the s=5
// identity copy into the staging loop, precompute separable tap tables
// (x:5x40, y:5x30) in LDS alongside staging, ONE barrier, then emit all
// 5 bilinear slices. Staging & barriers /6, tap VALU ~/2.5.
#define F_CPB 4                        // channels per block
#define F_CGRP (C_ / F_CPB)            // 128
#define F_TPB 512
#define F_BLOCKS (4 * F_CGRP)          // 512  (2 blocks/CU exactly)

// ws int layout: [block][cnt20|mnx20|mny20|mxx20|mxy20] * 300, then boxes[5*4]

__global__ void stats_k(const float* __restrict__ seg, int* __restrict__ ws) {
    __shared__ int s_cnt[K_CLS], s_mnx[K_CLS], s_mny[K_CLS], s_mxx[K_CLS], s_mxy[K_CLS];
    int t = threadIdx.x;
    if (t < K_CLS) { s_cnt[t] = 0; s_mnx[t] = WIN; s_mny[t] = HIN; s_mxx[t] = -1; s_mxy[t] = -1; }
    __syncthreads();

    int p = blockIdx.x * blockDim.x + t;                 // quad-pixel index, 0..76799
    const float4* base = (const float4*)(seg + (size_t)3 * K_CLS * NPIX) + p;
    float4 v = base[0];
    float b0 = v.x, b1 = v.y, b2 = v.z, b3 = v.w;
    int k0 = 0, k1 = 0, k2 = 0, k3 = 0;
    #pragma unroll
    for (int k = 1; k < K_CLS; k++) {                    // strict > : np.argmax tie-break
        float4 u = base[(size_t)k * (NPIX / 4)];
        if (u.x > b0) { b0 = u.x; k0 = k; }
        if (u.y > b1) { b1 = u.y; k1 = k; }
        if (u.z > b2) { b2 = u.z; k2 = k; }
        if (u.w > b3) { b3 = u.w; k3 = k; }
    }
    int x = (p * 4) % WIN, y = (p * 4) / WIN;            // quad never wraps a row (640%4==0)
    if (k0 == k1 && k1 == k2 && k2 == k3) {              // common case: uniform class
        atomicAdd(&s_cnt[k0], 4);
        atomicMin(&s_mnx[k0], x);     atomicMax(&s_mxx[k0], x + 3);
        atomicMin(&s_mny[k0], y);     atomicMax(&s_mxy[k0], y);
    } else {
        int ks[4] = {k0, k1, k2, k3};
        #pragma unroll
        for (int i = 0; i < 4; i++) {
            atomicAdd(&s_cnt[ks[i]], 1);
            atomicMin(&s_mnx[ks[i]], x + i);  atomicMax(&s_mxx[ks[i]], x + i);
            atomicMin(&s_mny[ks[i]], y);      atomicMax(&s_mxy[ks[i]], y);
        }
    }
    __syncthreads();
    if (t < 100) {                                       // per-block partial, plain store
        int a = t / 20, c = t % 20;
        int val = (a == 0) ? s_cnt[c] : (a == 1) ? s_mnx[c] : (a == 2) ? s_mny[c]
                : (a == 3) ? s_mxx[c] : s_mxy[c];
        ws[blockIdx.x * 100 + t] = val;
    }
}

// Parallel reduce 300 partial records -> final stats -> boxes.
// Also copies the 2050-float header (pool_x, NB, N) so the fused kernel's
// mapping is purely the x_cropped region (no per-thread header branch).
__global__ void plan_k(int* __restrict__ ws, const float* __restrict__ pool_x,
                       float* __restrict__ out) {
    __shared__ int part[10][100];
    __shared__ int st[100];
    int t = threadIdx.x;                 // 0..1023

    // header: 2048 floats of pool_x as 1024 float2, then {NB, N}
    ((float2*)out)[t] = ((const float2*)pool_x)[t];
    if (t == 0) { out[2048] = 5.0f; out[2049] = 4.0f; }

    if (t < 1000) {
        int c = t % 100, chunk = t / 100;
        int a = c / 20;
        int acc = (a == 0) ? 0 : (a == 1) ? WIN : (a == 2) ? HIN : -1;
        #pragma unroll
        for (int i = 0; i < 30; i++) {
            int v = ws[(chunk * 30 + i) * 100 + c];
            if (a == 0)      acc += v;
            else if (a <= 2) acc = v < acc ? v : acc;
            else             acc = v > acc ? v : acc;
        }
        part[chunk][c] = acc;
    }
    __syncthreads();
    if (t < 100) {
        int a = t / 20;
        int acc = part[0][t];
        #pragma unroll
        for (int i = 1; i < 10; i++) {
            int v = part[i][t];
            if (a == 0)      acc += v;
            else if (a <= 2) acc = v < acc ? v : acc;
            else             acc = v > acc ? v : acc;
        }
        st[t] = acc;
    }
    __syncthreads();
    if (t != 0) return;

    int* cnt = st;
    int* mnx = st + 20; int* mny = st + 40; int* mxx = st + 60; int* mxy = st + 80;
    int* nb  = ws + NODE_OFF;

    // np.unique -> sorted present ids; drop smallest present id
    int firstp = -1;
    for (int i = 0; i < K_CLS; i++) if (cnt[i] > 0) { firstp = i; break; }
    int order[K_CLS]; int nc = 0;
    for (int i = 0; i < K_CLS; i++)
        if (cnt[i] > 0 && i != firstp) order[nc++] = i;

    // stable insertion sort, descending by count
    for (int i = 1; i < nc; i++) {
        int key = order[i]; int j = i - 1;
        while (j >= 0 && cnt[order[j]] < cnt[key]) { order[j + 1] = order[j]; j--; }
        order[j + 1] = key;
    }

    int nsel = 0;
    for (int i = 0; i < nc && nsel < NB_ - 2; i++) {
        int b = order[i];
        if (cnt[b] > CNT_THRESH) {
            nb[nsel * 4 + 0] = mnx[b] >> 4;
            nb[nsel * 4 + 1] = mny[b] >> 4;
            nb[nsel * 4 + 2] = mxx[b] >> 4;
            nb[nsel * 4 + 3] = mxy[b] >> 4;
            nsel++;
        }
    }
    const int bb[5][4] = {
        {W_ / 4, H_ / 4, 3 * W_ / 4, 3 * H_ / 4},
        {0, 0, W_ / 3, H_},
        {0, 0, W_, H_ / 3},
        {2 * W_ / 3, 0, W_, H_},
        {0, 2 * H_ / 3, W_, H_}
    };
    for (int i = 0; nsel < NB_; i++, nsel++) {
        nb[nsel * 4 + 0] = bb[i][0];
        nb[nsel * 4 + 1] = bb[i][1];
        nb[nsel * 4 + 2] = bb[i][2];
        nb[nsel * 4 + 3] = bb[i][3];
    }
}

__global__ __launch_bounds__(F_TPB) void fuse_k(const float* __restrict__ feat,
                      const int* __restrict__ nb,
                      float* __restrict__ out) {
    __shared__ float sf[F_CPB * HW_];                    // 19.2 KB feat slice
    __shared__ int   s_xlo[NB_ * W_], s_xhi[NB_ * W_];   // per-crop x taps
    __shared__ float s_tx [NB_ * W_];
    __shared__ int   s_r0 [NB_ * H_], s_r1 [NB_ * H_];   // per-crop row bases (incl x0)
    __shared__ float s_ty [NB_ * H_];

    int t  = threadIdx.x;
    int n  = blockIdx.x / F_CGRP;                        // batch, 0..3
    int c0 = (blockIdx.x % F_CGRP) * F_CPB;              // channel group base

    // stage (n, c0..c0+3) slice into LDS; fuse the s=5 identity copy
    // (out slice 20+n has the same linear layout as feat).
    const float* src = feat + ((size_t)n * C_ + c0) * HW_;
    float* cdst = out + 2050 + (size_t)(20 + n) * ELEMS_PER_SN + (size_t)c0 * HW_;
    for (int i = t; i < (F_CPB * HW_) / 4; i += F_TPB) {
        f32x4 v = ((const f32x4*)src)[i];
        ((f32x4*)sf)[i] = v;
        // dest only 8B-aligned (2050%4==2) -> two f32x2 NT stores
        f32x2 lo = {v.x, v.y}, hi = {v.z, v.w};
        __builtin_nontemporal_store(lo, (f32x2*)(cdst + i * 4));
        __builtin_nontemporal_store(hi, (f32x2*)(cdst + i * 4 + 2));
    }

    // separable tap tables for all 5 crops (x: 5x40, y: 5x30).
    // Same math as R6 (test-passing): half-pixel centers, antialias inert,
    // CLAMP ORDER: hi tap = unclamped lo + 1, THEN clamp (R1 bug).
    if (t < NB_ * W_ + NB_ * H_) {                       // t < 350
        int isX = t < NB_ * W_;
        int b   = isX ? t / W_ : (t - NB_ * W_) / H_;
        int x0 = nb[b * 4 + 0], y0 = nb[b * 4 + 1];
        int x1 = nb[b * 4 + 2], y1 = nb[b * 4 + 3];
        int iw = max(x1 - x0, 1), ih = max(y1 - y0, 1);
        if (isX) {
            int w = t % W_;
            float fx = ((float)w + 0.5f) * (float)iw / (float)W_ - 0.5f;
            float fl = floorf(fx);
            int lo_u = (int)fl;                          // >= -1; <= iw-1 always
            s_tx[t]  = fx - fl;
            s_xlo[t] = max(lo_u, 0);
            s_xhi[t] = min(lo_u + 1, iw - 1);
        } else {
            int e = t - NB_ * W_;
            int h = e % H_;
            float fy = ((float)h + 0.5f) * (float)ih / (float)H_ - 0.5f;
            float fl = floorf(fy);
            int lo_u = (int)fl;
            int yl = max(lo_u, 0);
            int yh = min(lo_u + 1, ih - 1);
            int cb = y0 * W_ + x0;                       // crop base in channel slice
            s_ty[e] = fy - fl;
            s_r0[e] = cb + yl * W_;                      // max idx <= 1199, in-bounds
            s_r1[e] = cb + yh * W_;
        }
    }
    __syncthreads();

    // emit all 5 bilinear crop slices from the one staged slice
    for (int b = 0; b < NB_; b++) {
        float* ob = out + 2050 + (size_t)(5 * n + b) * ELEMS_PER_SN + (size_t)c0 * HW_;
        const int*   xlo = s_xlo + b * W_;
        const int*   xhi = s_xhi + b * W_;
        const float* txp = s_tx  + b * W_;
        const int*   r0p = s_r0  + b * H_;
        const int*   r1p = s_r1  + b * H_;
        const float* typ = s_ty  + b * H_;
        for (int hw = t; hw < HW_; hw += F_TPB) {
            int h = hw / W_;
            int w = hw - h * W_;
            int r0 = r0p[h], r1 = r1p[h];
            float ty = typ[h];
            int xl = xlo[w], xh = xhi[w];
            float tx = txp[w];
            int i00 = r0 + xl, i01 = r0 + xh;
            int i10 = r1 + xl, i11 = r1 + xh;
            float* op = ob + hw;
            #pragma unroll
            for (int j = 0; j < F_CPB; j++) {            // taps shared by channels
                const float* sp = sf + j * HW_;          // j*4800B folds into ds imm
                float v00 = sp[i00], v01 = sp[i01];
                float v10 = sp[i10], v11 = sp[i11];
                float top = v00 + tx * (v01 - v00);      // 3-FMA lerp
                float bot = v10 + tx * (v11 - v10);
                __builtin_nontemporal_store(top + ty * (bot - top), op + j * HW_);
            }
        }
    }
}

extern "C" void kernel_launch(void* const* d_in, const int* in_sizes, int n_in,
                              void* d_out, int out_size, void* d_ws, size_t ws_size,
                              hipStream_t stream) {
    const float* seg    = (const float*)d_in[0];
    const float* feat   = (const float*)d_in[1];
    const float* pool_x = (const float*)d_in[2];
    float* out = (float*)d_out;
    int* ws = (int*)d_ws;

    stats_k<<<NBLK_STATS, 256, 0, stream>>>(seg, ws);
    plan_k<<<1, 1024, 0, stream>>>(ws, pool_x, out);
    fuse_k<<<F_BLOCKS, F_TPB, 0, stream>>>(feat, ws + NODE_OFF, out);
}